// Round 10
// baseline (255.944 us; speedup 1.0000x reference)
//
#include <hip/hip_runtime.h>
#include <hip/hip_bf16.h>

#define DM 1024
#define NH 16
#define HD 64
#define B_ 2
#define S_ 2048
#define M_ (B_*S_)   // 4096

typedef __attribute__((ext_vector_type(8))) short bf16x8;
typedef __attribute__((ext_vector_type(4))) float f32x4;
typedef __attribute__((ext_vector_type(4))) unsigned uint32x4;
typedef __attribute__((ext_vector_type(2))) unsigned uint32x2;

__device__ __forceinline__ float bf2f(ushort u) {
  union { unsigned u32; float f; } c; c.u32 = ((unsigned)u) << 16; return c.f;
}
__device__ __forceinline__ ushort f2bf(float f) {
  union { float f; unsigned u32; } c; c.f = f;
  unsigned u = c.u32;
  unsigned r = (u + 0x7fffu + ((u >> 16) & 1u)) >> 16;
  return (ushort)r;
}
__device__ __forceinline__ unsigned fbits(float f) {
  union { float f; unsigned u; } c; c.f = f; return c.u;
}

// async global->LDS, 16 B per lane; LDS dest = wave-uniform base + lane*16
__device__ __forceinline__ void async16(const ushort* g, ushort* l) {
  __builtin_amdgcn_global_load_lds((const __attribute__((address_space(1))) void*)g,
                                   (__attribute__((address_space(3))) void*)l, 16, 0, 0);
}

// gfx950 cross-lane swaps via BUILTINS (not inline asm): permlane has a VALU-write ->
// permlane-read hazard requiring compiler-inserted wait states; the hazard recognizer
// can't see into inline asm (v9/v10 raw-asm miscompute; v11 builtins fixed it).
__device__ __forceinline__ void pswap32(unsigned& a, unsigned& b) {
  uint32x2 r = __builtin_amdgcn_permlane32_swap(a, b, false, false);
  a = r[0]; b = r[1];
}
__device__ __forceinline__ void pswap16(unsigned& a, unsigned& b) {
  uint32x2 r = __builtin_amdgcn_permlane16_swap(a, b, false, false);
  a = r[0]; b = r[1];
}

// ---- fused prep: z<4 -> fp32 W[k][n] -> bf16 Wt[n][k]; z==4 -> fp32 x -> bf16 ----
__global__ void cvt_prep(const float* __restrict__ x, const float* __restrict__ W0,
                         const float* __restrict__ W1, const float* __restrict__ W2,
                         const float* __restrict__ W3, ushort* __restrict__ wt,
                         ushort* __restrict__ xb) {
  __shared__ float tile[64][65];
  int z = blockIdx.z;
  int tx = threadIdx.x, ty = threadIdx.y;   // block (64,4)
  if (z == 4) {
    int tid = ty * 64 + tx;
    size_t base4 = ((size_t)blockIdx.y * 16 + blockIdx.x) * 4096;  // float4 units
    const float4* xv = (const float4*)x;
    ushort4* ov = (ushort4*)xb;
    #pragma unroll
    for (int k = 0; k < 16; ++k) {
      float4 v = xv[base4 + k * 256 + tid];
      ushort4 o;
      o.x = f2bf(v.x); o.y = f2bf(v.y); o.z = f2bf(v.z); o.w = f2bf(v.w);
      ov[base4 + k * 256 + tid] = o;
    }
    return;
  }
  const float* W = (z == 0) ? W0 : (z == 1) ? W1 : (z == 2) ? W2 : W3;
  ushort* Wt = wt + (size_t)z * (DM * DM);
  int c0 = blockIdx.x * 64, r0 = blockIdx.y * 64;
  #pragma unroll
  for (int i = ty; i < 64; i += 4) tile[i][tx] = W[(size_t)(r0 + i) * DM + c0 + tx];
  __syncthreads();
  #pragma unroll
  for (int i = ty; i < 64; i += 4) Wt[(size_t)(c0 + i) * DM + r0 + tx] = f2bf(tile[tx][i]);
}

// ---------------- MFMA GEMM: C[M][N] = A[M][K] * Bt[N][K]^T ----------------
// 128(M) x BN(N) tile, 4 waves (2x2), BK=32, global_load_lds width=16 staging.
// MODE 0: float C[m*DM+n]
// MODE 1: bf16 head layout C[((b*NH+h)*S_+s)*HD+d]             (Q, K)
// MODE 2: bf16 V^T layout C[((b*NH+h)*HD+d)*S_+s] via LDS transpose (coalesced)
template <int MODE, int BN>
__device__ __forceinline__ void gemm_body(const ushort* __restrict__ A,
                                          const ushort* __restrict__ Bt,
                                          ushort* __restrict__ Cb,
                                          float* __restrict__ Cf,
                                          ushort* As, ushort* Bs, ushort* Ts) {
  const int K = DM;
  constexpr int CN = BN / 32;                   // n-frags per wave
  int m0 = blockIdx.y * 128;
  int n0 = blockIdx.x * BN;
  int t = threadIdx.x;
  int lane = t & 63, wave = t >> 6;
  int wm = (wave >> 1) * 64, wn = (wave & 1) * (BN / 2);
  int lrow = lane & 15, quad = lane >> 4;

  int Ra = wave * 32;                           // A rows staged by this wave
  int Rb = wave * (BN / 4);                     // B rows staged by this wave
  int srow = lane >> 2, scol = (lane & 3) * 8;  // per-lane 16B chunk within 16-row group

  f32x4 acc[4][CN];
  #pragma unroll
  for (int r = 0; r < 4; ++r)
    #pragma unroll
    for (int c = 0; c < CN; ++c) acc[r][c] = (f32x4){0.f, 0.f, 0.f, 0.f};

  for (int k0 = 0; k0 < K; k0 += 32) {
    const ushort* ga = A + (size_t)(m0 + Ra + srow) * K + k0 + scol;
    const ushort* gb = Bt + (size_t)(n0 + Rb + srow) * K + k0 + scol;
    async16(ga,          As + Ra * 32);
    async16(ga + 16 * K, As + (Ra + 16) * 32);
    async16(gb,          Bs + Rb * 32);
    if (BN == 128) async16(gb + 16 * K, Bs + (Rb + 16) * 32);
    __syncthreads();

    bf16x8 af[4], bfr[CN];
    #pragma unroll
    for (int r = 0; r < 4; ++r)
      af[r] = *(const bf16x8*)(As + (wm + r * 16 + lrow) * 32 + quad * 8);
    #pragma unroll
    for (int c = 0; c < CN; ++c)
      bfr[c] = *(const bf16x8*)(Bs + (wn + c * 16 + lrow) * 32 + quad * 8);
    #pragma unroll
    for (int r = 0; r < 4; ++r)
      #pragma unroll
      for (int c = 0; c < CN; ++c)
        acc[r][c] = __builtin_amdgcn_mfma_f32_16x16x32_bf16(af[r], bfr[c], acc[r][c], 0, 0, 0);
    __syncthreads();
  }

  if constexpr (MODE == 2) {
    // transpose through LDS in two half-passes, then coalesced V^T rows.
    // Ts ALIASES As/Bs (dead after K-loop's trailing barrier).
    int bb = m0 >> 11;            // batch (block never straddles b)
    int s0base = m0 & 2047;
    #pragma unroll
    for (int H = 0; H < 2; ++H) {
      __syncthreads();            // Ts reuse guard (and As/Bs death guard on H=0)
      if ((wave >> 1) == H) {
        #pragma unroll
        for (int r = 0; r < 4; ++r)
          #pragma unroll
          for (int c = 0; c < 4; ++c) {
            uint2 pk;
            pk.x = (unsigned)f2bf(acc[r][c][0]) | ((unsigned)f2bf(acc[r][c][1]) << 16);
            pk.y = (unsigned)f2bf(acc[r][c][2]) | ((unsigned)f2bf(acc[r][c][3]) << 16);
            *(uint2*)(Ts + (wn + c * 16 + lrow) * 72 + r * 16 + quad * 4) = pk;
          }
      }
      __syncthreads();
      #pragma unroll
      for (int i = 0; i < 4; ++i) {
        int id = t + i * 256;
        int nn = id >> 3, col = (id & 7) * 8;
        uint4 v = *(const uint4*)(Ts + nn * 72 + col);
        int h2 = (n0 >> 6) + (nn >> 6), d2 = nn & 63;
        size_t dst = (((size_t)(bb * NH + h2)) * HD + d2) * (size_t)S_ + s0base + H * 64 + col;
        *(uint4*)(Cb + dst) = v;
      }
    }
  } else {
    // epilogue: C/D layout col=lane&15, row=quad*4+e
    #pragma unroll
    for (int r = 0; r < 4; ++r) {
      #pragma unroll
      for (int c = 0; c < CN; ++c) {
        #pragma unroll
        for (int e = 0; e < 4; ++e) {
          int m = m0 + wm + r * 16 + quad * 4 + e;
          int n = n0 + wn + c * 16 + lrow;
          if (MODE == 0) {
            Cf[(size_t)m * DM + n] = acc[r][c][e];
          } else {
            int b = m >> 11, s = m & 2047, h = n >> 6, d = n & 63;
            Cb[(((size_t)(b * NH + h)) * S_ + s) * HD + d] = f2bf(acc[r][c][e]);
          }
        }
      }
    }
  }
}

// single dispatch for Q, K, V (z = 0,1,2); Ts unioned with As/Bs -> 18.4 KB LDS
__global__ __launch_bounds__(256, 3) void gemm_qkv(const ushort* __restrict__ A,
                                                   const ushort* __restrict__ wt,
                                                   ushort* __restrict__ qkv) {
  __shared__ __align__(16) ushort smem[9216];   // As[0:4096) Bs[4096:8192); Ts aliases [0:9216)
  ushort* As = smem;
  ushort* Bs = smem + 4096;
  ushort* Ts = smem;
  int z = blockIdx.z;
  if (z < 2)
    gemm_body<1, 128>(A, wt + (size_t)z * (DM * DM), qkv + (size_t)z * ((size_t)M_ * DM),
                      nullptr, As, Bs, Ts);
  else
    gemm_body<2, 128>(A, wt + (size_t)2 * (DM * DM), qkv + (size_t)2 * ((size_t)M_ * DM),
                      nullptr, As, Bs, Ts);
}

// 128x64 tiles -> grid 512, 12 KB LDS, 3 blocks/CU target
__global__ __launch_bounds__(256, 3) void gemm_out(const ushort* __restrict__ A,
                                                   const ushort* __restrict__ wt,
                                                   float* __restrict__ C) {
  __shared__ __align__(16) ushort As[128 * 32];
  __shared__ __align__(16) ushort Bs[64 * 32];
  gemm_body<0, 64>(A, wt, nullptr, C, As, Bs, nullptr);
}

// ---------------- MFMA flash attention v15: zero-LDS, zero-barrier ----------------
// v14 post-mortem: halving LDS traffic (bank conflicts 4.33M->2.23M confirms) did NOT
// move time (43.8->46us) -> LDS pipe was not the limiter. VALUBusy 28% (~13us work),
// MfmaUtil 13.6% (~6us); per-step measured cost 1670 cyc vs ~600 cyc/wave of issue ->
// the barrier-lockstep schedule exposes ~1000 cyc/step of latency that 2-4 waves/SIMD
// cannot hide. The invariant across v7-v14 is the LDS double-buffer + barriers.
// v15 observation: the K-fragment a lane needs is K[kt+c*16+lrow][quad*8..+8] and the
// V-fragment is V^T[c*16+lrow][kt+quad*8..+8] — both are PLAIN 16B CONTIGUOUS chunks
// of global memory. All 4 waves of a block load IDENTICAL K/V fragments (wave affects
// only Q rows) -> L1 serves 3 of 4 waves; per-XCD K/V footprint (2MB) is L2-resident
// (FETCH 12.3MB proven). So: load fragments directly with global_load_dwordx4.
// Removes ALL LDS, ALL ds_write/ds_read, vmcnt(0) drains, and EVERY __syncthreads —
// waves run fully independently; latency hidden by TLP (LDS=0 -> occupancy limited
// only by VGPR, ~3-4 waves/SIMD).
// Addressing: SGPR-uniform base advances by one K-tile per step; per-lane voffsets are
// loop-invariant. Math/masks = v12 (proven): masked exactly at kt==kend.
#define EXPC 0.18033688011f   // 0.125 * log2(e)

struct AttnState {
  f32x4 o[4];
  float l;
};

template <bool MASKED>
__device__ __forceinline__ void attn_tile_compute(
    int q0, int kt, bf16x8 qf0, bf16x8 qf1,
    const bf16x8 kf0[4], const bf16x8 kf1[4],
    const bf16x8 vf0[4], const bf16x8 vf1[4],
    AttnState& st, int lrow, int quad) {
  f32x4 s[4];
  #pragma unroll
  for (int c = 0; c < 4; ++c) {
    f32x4 z = (f32x4){0.f, 0.f, 0.f, 0.f};
    z = __builtin_amdgcn_mfma_f32_16x16x32_bf16(kf0[c], qf0, z, 0, 0, 0);
    z = __builtin_amdgcn_mfma_f32_16x16x32_bf16(kf1[c], qf1, z, 0, 0, 0);
    s[c] = z;
  }
  int q = q0 + lrow;
  unsigned w0[4], w1[4];   // W[c][0], W[c][1]: packed bf16 pairs, keys 16c+4*quad+{0,1},{2,3}
  #pragma unroll
  for (int c = 0; c < 4; ++c) {
    float pv[4];
    #pragma unroll
    for (int e = 0; e < 4; ++e) {
      float v = __builtin_amdgcn_exp2f(s[c][e] * EXPC);
      if (MASKED) {
        int key = kt + c * 16 + quad * 4 + e;
        v = (key <= q) ? v : 0.f;
      }
      pv[e] = v;
      st.l += v;
    }
    w0[c] = __builtin_amdgcn_perm(fbits(pv[1]), fbits(pv[0]), 0x07060302u);
    w1[c] = __builtin_amdgcn_perm(fbits(pv[3]), fbits(pv[2]), 0x07060302u);
  }

  // redistribute: pair (W[c], W[c+1]) -> permlane32_swap + permlane16_swap.
  unsigned a0 = w0[0], b0 = w0[1]; pswap32(a0, b0); pswap16(a0, b0);
  unsigned a1 = w1[0], b1 = w1[1]; pswap32(a1, b1); pswap16(a1, b1);
  unsigned c0 = w0[2], d0 = w0[3]; pswap32(c0, d0); pswap16(c0, d0);
  unsigned c1 = w1[2], d1 = w1[3]; pswap32(c1, d1); pswap16(c1, d1);
  union { uint32x4 u; bf16x8 b; } P0, P1;
  P0.u = (uint32x4){a0, a1, b0, b1};   // keys 8*quad+0..7   (A-frag, k=0..31)
  P1.u = (uint32x4){c0, c1, d0, d1};   // keys 32+8*quad+0..7 (A-frag, k=32..63)

  #pragma unroll
  for (int dt = 0; dt < 4; ++dt) {
    st.o[dt] = __builtin_amdgcn_mfma_f32_16x16x32_bf16(P0.b, vf0[dt], st.o[dt], 0, 0, 0);
    st.o[dt] = __builtin_amdgcn_mfma_f32_16x16x32_bf16(P1.b, vf1[dt], st.o[dt], 0, 0, 0);
  }
}

__global__ __launch_bounds__(256, 2) void attn_mfma(const ushort* __restrict__ Q,
                                                    const ushort* __restrict__ Kmat,
                                                    const ushort* __restrict__ Vt,
                                                    ushort* __restrict__ ctx) {
  int t = threadIdx.x;
  int lane = t & 63, wave = t >> 6;
  int lrow = lane & 15, quad = lane >> 4;
  int n = blockIdx.x;                  // 0..1023
  int c = n & 255, g = n >> 8;         // balanced co-resident mapping (v12)
  int bh = c & 31;                     // bh%8 == n%8 -> head->XCD locality
  int j = (c >> 5) & 7;
  int qt = (g == 0) ? j : (g == 1) ? (15 - j) : (g == 2) ? (16 + j) : (31 - j);
  const ushort* Kb = Kmat + (size_t)bh * S_ * HD;
  const ushort* Vb = Vt + (size_t)bh * HD * S_;
  int b = bh >> 4, h = bh & 15;

  int q0 = qt * 64 + wave * 16;
  const ushort* Qp = Q + ((size_t)bh * S_ + q0) * HD;
  bf16x8 qf0 = *(const bf16x8*)(Qp + (size_t)lrow * HD + quad * 8);
  bf16x8 qf1 = *(const bf16x8*)(Qp + (size_t)lrow * HD + 32 + quad * 8);

  AttnState st;
  #pragma unroll
  for (int i = 0; i < 4; ++i) st.o[i] = (f32x4){0.f, 0.f, 0.f, 0.f};
  st.l = 0.f;

  int kend = qt * 64;

  // loop-invariant per-lane element offsets
  int kq = quad * 8;                          // K col / V key sub-offset
  for (int kt = 0; kt <= kend; kt += 64) {
    const ushort* Kp = Kb + (size_t)kt * HD;  // uniform advance per step
    const ushort* Vp = Vb + kt;

    bf16x8 kf0[4], kf1[4], vf0[4], vf1[4];
    #pragma unroll
    for (int c2 = 0; c2 < 4; ++c2) {
      const ushort* kr = Kp + (size_t)(c2 * 16 + lrow) * HD + kq;
      kf0[c2] = *(const bf16x8*)(kr);
      kf1[c2] = *(const bf16x8*)(kr + 32);
      const ushort* vr = Vp + (size_t)(c2 * 16 + lrow) * S_ + kq;
      vf0[c2] = *(const bf16x8*)(vr);
      vf1[c2] = *(const bf16x8*)(vr + 32);
    }

    if (kt < kend)
      attn_tile_compute<false>(q0, kt, qf0, qf1, kf0, kf1, vf0, vf1, st, lrow, quad);
    else
      attn_tile_compute<true>(q0, kt, qf0, qf1, kf0, kf1, vf0, vf1, st, lrow, quad);
  }

  {
    float l = st.l;
    l += __shfl_xor(l, 16);
    l += __shfl_xor(l, 32);
    float rl = 1.0f / l;
    #pragma unroll
    for (int e = 0; e < 4; ++e) {
      float rinv = __shfl(rl, quad * 4 + e);
      int q = q0 + quad * 4 + e;
      #pragma unroll
      for (int dt = 0; dt < 4; ++dt)
        ctx[((size_t)b * S_ + q) * DM + h * HD + dt * 16 + lrow] = f2bf(st.o[dt][e] * rinv);
    }
  }
}

// ---------------- launch ----------------
extern "C" void kernel_launch(void* const* d_in, const int* in_sizes, int n_in,
                              void* d_out, int out_size, void* d_ws, size_t ws_size,
                              hipStream_t stream) {
  const float* x  = (const float*)d_in[0];
  const float* Wq = (const float*)d_in[1];
  const float* Wk = (const float*)d_in[2];
  const float* Wv = (const float*)d_in[3];
  const float* Wo = (const float*)d_in[4];
  float* out = (float*)d_out;
  ushort* ws = (ushort*)d_ws;

  ushort* xb  = ws;                                   // 4M elem bf16 x
  ushort* wt  = xb + (size_t)M_ * DM;                 // 4 x 1M elem (Wq^T,Wk^T,Wv^T,Wo^T) bf16
  ushort* qkv = wt + (size_t)4 * DM * DM;             // Q,K [b,h,s,d]; V^T [b,h,d,s] bf16
  ushort* ctx = qkv + (size_t)3 * M_ * DM;            // 4M elem [B,S,DM] bf16

  cvt_prep<<<dim3(16, 16, 5), dim3(64, 4), 0, stream>>>(x, Wq, Wk, Wv, Wo, wt, xb);
  gemm_qkv<<<dim3(DM / 128, M_ / 128, 3), 256, 0, stream>>>(xb, wt, qkv);
  attn_mfma<<<dim3(32 * B_ * NH), 256, 0, stream>>>(qkv, qkv + (size_t)M_ * DM,
                                                    qkv + (size_t)2 * M_ * DM, ctx);
  gemm_out<<<dim3(DM / 64, M_ / 128), 256, 0, stream>>>(ctx, wt + (size_t)3 * DM * DM, out);
}

// Round 12
// 253.695 us; speedup vs baseline: 1.0089x; 1.0089x over previous
//
#include <hip/hip_runtime.h>
#include <hip/hip_bf16.h>

#define DM 1024
#define NH 16
#define HD 64
#define B_ 2
#define S_ 2048
#define M_ (B_*S_)   // 4096

typedef __attribute__((ext_vector_type(8))) short bf16x8;
typedef __attribute__((ext_vector_type(4))) float f32x4;
typedef __attribute__((ext_vector_type(4))) unsigned uint32x4;
typedef __attribute__((ext_vector_type(2))) unsigned uint32x2;

__device__ __forceinline__ float bf2f(ushort u) {
  union { unsigned u32; float f; } c; c.u32 = ((unsigned)u) << 16; return c.f;
}
__device__ __forceinline__ ushort f2bf(float f) {
  union { float f; unsigned u32; } c; c.f = f;
  unsigned u = c.u32;
  unsigned r = (u + 0x7fffu + ((u >> 16) & 1u)) >> 16;
  return (ushort)r;
}
__device__ __forceinline__ unsigned fbits(float f) {
  union { float f; unsigned u; } c; c.f = f; return c.u;
}

// async global->LDS, 16 B per lane; LDS dest = wave-uniform base + lane*16
__device__ __forceinline__ void async16(const ushort* g, ushort* l) {
  __builtin_amdgcn_global_load_lds((const __attribute__((address_space(1))) void*)g,
                                   (__attribute__((address_space(3))) void*)l, 16, 0, 0);
}

// gfx950 cross-lane swaps via BUILTINS (not inline asm): permlane has a VALU-write ->
// permlane-read hazard requiring compiler-inserted wait states; the hazard recognizer
// can't see into inline asm (v9/v10 raw-asm miscompute; v11 builtins fixed it).
__device__ __forceinline__ void pswap32(unsigned& a, unsigned& b) {
  uint32x2 r = __builtin_amdgcn_permlane32_swap(a, b, false, false);
  a = r[0]; b = r[1];
}
__device__ __forceinline__ void pswap16(unsigned& a, unsigned& b) {
  uint32x2 r = __builtin_amdgcn_permlane16_swap(a, b, false, false);
  a = r[0]; b = r[1];
}

// ---- fused prep: z<4 -> fp32 W[k][n] -> bf16 Wt[n][k]; z==4 -> fp32 x -> bf16 ----
__global__ void cvt_prep(const float* __restrict__ x, const float* __restrict__ W0,
                         const float* __restrict__ W1, const float* __restrict__ W2,
                         const float* __restrict__ W3, ushort* __restrict__ wt,
                         ushort* __restrict__ xb) {
  __shared__ float tile[64][65];
  int z = blockIdx.z;
  int tx = threadIdx.x, ty = threadIdx.y;   // block (64,4)
  if (z == 4) {
    int tid = ty * 64 + tx;
    size_t base4 = ((size_t)blockIdx.y * 16 + blockIdx.x) * 4096;  // float4 units
    const float4* xv = (const float4*)x;
    ushort4* ov = (ushort4*)xb;
    #pragma unroll
    for (int k = 0; k < 16; ++k) {
      float4 v = xv[base4 + k * 256 + tid];
      ushort4 o;
      o.x = f2bf(v.x); o.y = f2bf(v.y); o.z = f2bf(v.z); o.w = f2bf(v.w);
      ov[base4 + k * 256 + tid] = o;
    }
    return;
  }
  const float* W = (z == 0) ? W0 : (z == 1) ? W1 : (z == 2) ? W2 : W3;
  ushort* Wt = wt + (size_t)z * (DM * DM);
  int c0 = blockIdx.x * 64, r0 = blockIdx.y * 64;
  #pragma unroll
  for (int i = ty; i < 64; i += 4) tile[i][tx] = W[(size_t)(r0 + i) * DM + c0 + tx];
  __syncthreads();
  #pragma unroll
  for (int i = ty; i < 64; i += 4) Wt[(size_t)(c0 + i) * DM + r0 + tx] = f2bf(tile[tx][i]);
}

// ---------------- MFMA GEMM: C[M][N] = A[M][K] * Bt[N][K]^T ----------------
// 128(M) x BN(N) tile, 4 waves (2x2), BK=32, global_load_lds width=16 staging.
// MODE 0: float C[m*DM+n]
// MODE 1: bf16 head layout C[((b*NH+h)*S_+s)*HD+d]             (Q, K)
// MODE 2: bf16 V in kt-TILE-MAJOR layout C[((bh*32 + s/64)*64 + d)*64 + (s&63)]
//         via LDS transpose (coalesced 16B writes, 128B thread stride)
template <int MODE, int BN>
__device__ __forceinline__ void gemm_body(const ushort* __restrict__ A,
                                          const ushort* __restrict__ Bt,
                                          ushort* __restrict__ Cb,
                                          float* __restrict__ Cf,
                                          ushort* As, ushort* Bs, ushort* Ts) {
  const int K = DM;
  constexpr int CN = BN / 32;                   // n-frags per wave
  int m0 = blockIdx.y * 128;
  int n0 = blockIdx.x * BN;
  int t = threadIdx.x;
  int lane = t & 63, wave = t >> 6;
  int wm = (wave >> 1) * 64, wn = (wave & 1) * (BN / 2);
  int lrow = lane & 15, quad = lane >> 4;

  int Ra = wave * 32;                           // A rows staged by this wave
  int Rb = wave * (BN / 4);                     // B rows staged by this wave
  int srow = lane >> 2, scol = (lane & 3) * 8;  // per-lane 16B chunk within 16-row group

  f32x4 acc[4][CN];
  #pragma unroll
  for (int r = 0; r < 4; ++r)
    #pragma unroll
    for (int c = 0; c < CN; ++c) acc[r][c] = (f32x4){0.f, 0.f, 0.f, 0.f};

  for (int k0 = 0; k0 < K; k0 += 32) {
    const ushort* ga = A + (size_t)(m0 + Ra + srow) * K + k0 + scol;
    const ushort* gb = Bt + (size_t)(n0 + Rb + srow) * K + k0 + scol;
    async16(ga,          As + Ra * 32);
    async16(ga + 16 * K, As + (Ra + 16) * 32);
    async16(gb,          Bs + Rb * 32);
    if (BN == 128) async16(gb + 16 * K, Bs + (Rb + 16) * 32);
    __syncthreads();

    bf16x8 af[4], bfr[CN];
    #pragma unroll
    for (int r = 0; r < 4; ++r)
      af[r] = *(const bf16x8*)(As + (wm + r * 16 + lrow) * 32 + quad * 8);
    #pragma unroll
    for (int c = 0; c < CN; ++c)
      bfr[c] = *(const bf16x8*)(Bs + (wn + c * 16 + lrow) * 32 + quad * 8);
    #pragma unroll
    for (int r = 0; r < 4; ++r)
      #pragma unroll
      for (int c = 0; c < CN; ++c)
        acc[r][c] = __builtin_amdgcn_mfma_f32_16x16x32_bf16(af[r], bfr[c], acc[r][c], 0, 0, 0);
    __syncthreads();
  }

  if constexpr (MODE == 2) {
    // transpose through LDS in two half-passes, then coalesced tile-major V writes.
    // Ts ALIASES As/Bs (dead after K-loop's trailing barrier).
    int bb = m0 >> 11;            // batch (block never straddles b)
    int s0base = m0 & 2047;
    #pragma unroll
    for (int H = 0; H < 2; ++H) {
      __syncthreads();            // Ts reuse guard (and As/Bs death guard on H=0)
      if ((wave >> 1) == H) {
        #pragma unroll
        for (int r = 0; r < 4; ++r)
          #pragma unroll
          for (int c = 0; c < 4; ++c) {
            uint2 pk;
            pk.x = (unsigned)f2bf(acc[r][c][0]) | ((unsigned)f2bf(acc[r][c][1]) << 16);
            pk.y = (unsigned)f2bf(acc[r][c][2]) | ((unsigned)f2bf(acc[r][c][3]) << 16);
            *(uint2*)(Ts + (wn + c * 16 + lrow) * 72 + r * 16 + quad * 4) = pk;
          }
      }
      __syncthreads();
      int tt = (s0base >> 6) + H;   // kt-tile index for this half-pass
      #pragma unroll
      for (int i = 0; i < 4; ++i) {
        int id = t + i * 256;
        int nn = id >> 3, col = (id & 7) * 8;
        uint4 v = *(const uint4*)(Ts + nn * 72 + col);
        int h2 = (n0 >> 6) + (nn >> 6), d2 = nn & 63;
        // V[bh][tt][d][64 keys]: fragment for (kt,c2*16+lrow,quad) is contiguous like K
        size_t dst = (((size_t)(bb * NH + h2) * 32 + tt) * 64 + d2) * 64 + col;
        *(uint4*)(Cb + dst) = v;
      }
    }
  } else {
    // epilogue: C/D layout col=lane&15, row=quad*4+e
    #pragma unroll
    for (int r = 0; r < 4; ++r) {
      #pragma unroll
      for (int c = 0; c < CN; ++c) {
        #pragma unroll
        for (int e = 0; e < 4; ++e) {
          int m = m0 + wm + r * 16 + quad * 4 + e;
          int n = n0 + wn + c * 16 + lrow;
          if (MODE == 0) {
            Cf[(size_t)m * DM + n] = acc[r][c][e];
          } else {
            int b = m >> 11, s = m & 2047, h = n >> 6, d = n & 63;
            Cb[(((size_t)(b * NH + h)) * S_ + s) * HD + d] = f2bf(acc[r][c][e]);
          }
        }
      }
    }
  }
}

// single dispatch for Q, K, V (z = 0,1,2); Ts unioned with As/Bs -> 18.4 KB LDS
__global__ __launch_bounds__(256, 3) void gemm_qkv(const ushort* __restrict__ A,
                                                   const ushort* __restrict__ wt,
                                                   ushort* __restrict__ qkv) {
  __shared__ __align__(16) ushort smem[9216];   // As[0:4096) Bs[4096:8192); Ts aliases [0:9216)
  ushort* As = smem;
  ushort* Bs = smem + 4096;
  ushort* Ts = smem;
  int z = blockIdx.z;
  if (z < 2)
    gemm_body<1, 128>(A, wt + (size_t)z * (DM * DM), qkv + (size_t)z * ((size_t)M_ * DM),
                      nullptr, As, Bs, Ts);
  else
    gemm_body<2, 128>(A, wt + (size_t)2 * (DM * DM), qkv + (size_t)2 * ((size_t)M_ * DM),
                      nullptr, As, Bs, Ts);
}

// 128x64 tiles -> grid 512, 12 KB LDS, 3 blocks/CU target
__global__ __launch_bounds__(256, 3) void gemm_out(const ushort* __restrict__ A,
                                                   const ushort* __restrict__ wt,
                                                   float* __restrict__ C) {
  __shared__ __align__(16) ushort As[128 * 32];
  __shared__ __align__(16) ushort Bs[64 * 32];
  gemm_body<0, 64>(A, wt, nullptr, C, As, Bs, nullptr);
}

// ---------------- MFMA flash attention v16: zero-LDS + tile-major V ----------------
// v15 post-mortem: zero-LDS direction exposed the real cost — the V^T fragment load
// (lane stride S_=4KB) scattered each global_load_dwordx4 over 16 cache lines ->
// ~128 serialized VMEM transactions/wave-step -> ~4.6k cyc/step, no cross-wave
// overlap (dur 126us, VALUBusy 11%). K loads (128B lane stride -> one contiguous
// 2KB span per instruction) were fine. The deleted LDS staging had been doing the
// V gather once per block, coalesced.
// v16: keep v15's zero-LDS/zero-barrier structure; fix the LAYOUT instead. V is now
// produced kt-tile-major: V[bh][tile=s/64][d=0..63][64 keys]. The attn fragment
// (kt, c2*16+lrow, quad) sits at tilebase + row*128B + quad*16B — identical
// coalescing to K (2KB contiguous span per instruction, ~8x fewer VMEM txns).
// All 4 waves of a block load identical K/V bytes -> L1 serves 3 of 4; per-XCD
// K/V footprint 2MB is L2-resident (FETCH 12.3MB proven).
#define EXPC 0.18033688011f   // 0.125 * log2(e)

struct AttnState {
  f32x4 o[4];
  float l;
};

template <bool MASKED>
__device__ __forceinline__ void attn_tile_compute(
    int q0, int kt, bf16x8 qf0, bf16x8 qf1,
    const bf16x8 kf0[4], const bf16x8 kf1[4],
    const bf16x8 vf0[4], const bf16x8 vf1[4],
    AttnState& st, int lrow, int quad) {
  f32x4 s[4];
  #pragma unroll
  for (int c = 0; c < 4; ++c) {
    f32x4 z = (f32x4){0.f, 0.f, 0.f, 0.f};
    z = __builtin_amdgcn_mfma_f32_16x16x32_bf16(kf0[c], qf0, z, 0, 0, 0);
    z = __builtin_amdgcn_mfma_f32_16x16x32_bf16(kf1[c], qf1, z, 0, 0, 0);
    s[c] = z;
  }
  int q = q0 + lrow;
  unsigned w0[4], w1[4];   // W[c][0], W[c][1]: packed bf16 pairs, keys 16c+4*quad+{0,1},{2,3}
  #pragma unroll
  for (int c = 0; c < 4; ++c) {
    float pv[4];
    #pragma unroll
    for (int e = 0; e < 4; ++e) {
      float v = __builtin_amdgcn_exp2f(s[c][e] * EXPC);
      if (MASKED) {
        int key = kt + c * 16 + quad * 4 + e;
        v = (key <= q) ? v : 0.f;
      }
      pv[e] = v;
      st.l += v;
    }
    w0[c] = __builtin_amdgcn_perm(fbits(pv[1]), fbits(pv[0]), 0x07060302u);
    w1[c] = __builtin_amdgcn_perm(fbits(pv[3]), fbits(pv[2]), 0x07060302u);
  }

  // redistribute: pair (W[c], W[c+1]) -> permlane32_swap + permlane16_swap.
  unsigned a0 = w0[0], b0 = w0[1]; pswap32(a0, b0); pswap16(a0, b0);
  unsigned a1 = w1[0], b1 = w1[1]; pswap32(a1, b1); pswap16(a1, b1);
  unsigned c0 = w0[2], d0 = w0[3]; pswap32(c0, d0); pswap16(c0, d0);
  unsigned c1 = w1[2], d1 = w1[3]; pswap32(c1, d1); pswap16(c1, d1);
  union { uint32x4 u; bf16x8 b; } P0, P1;
  P0.u = (uint32x4){a0, a1, b0, b1};   // keys 8*quad+0..7   (A-frag, k=0..31)
  P1.u = (uint32x4){c0, c1, d0, d1};   // keys 32+8*quad+0..7 (A-frag, k=32..63)

  #pragma unroll
  for (int dt = 0; dt < 4; ++dt) {
    st.o[dt] = __builtin_amdgcn_mfma_f32_16x16x32_bf16(P0.b, vf0[dt], st.o[dt], 0, 0, 0);
    st.o[dt] = __builtin_amdgcn_mfma_f32_16x16x32_bf16(P1.b, vf1[dt], st.o[dt], 0, 0, 0);
  }
}

__global__ __launch_bounds__(256, 2) void attn_mfma(const ushort* __restrict__ Q,
                                                    const ushort* __restrict__ Kmat,
                                                    const ushort* __restrict__ Vt,
                                                    ushort* __restrict__ ctx) {
  int t = threadIdx.x;
  int lane = t & 63, wave = t >> 6;
  int lrow = lane & 15, quad = lane >> 4;
  int n = blockIdx.x;                  // 0..1023
  int c = n & 255, g = n >> 8;         // balanced co-resident mapping (v12)
  int bh = c & 31;                     // bh%8 == n%8 -> head->XCD locality
  int j = (c >> 5) & 7;
  int qt = (g == 0) ? j : (g == 1) ? (15 - j) : (g == 2) ? (16 + j) : (31 - j);
  const ushort* Kb = Kmat + (size_t)bh * S_ * HD;
  const ushort* Vb = Vt + (size_t)bh * S_ * HD;   // tile-major: [32 tiles][64 d][64 keys]
  int b = bh >> 4, h = bh & 15;

  int q0 = qt * 64 + wave * 16;
  const ushort* Qp = Q + ((size_t)bh * S_ + q0) * HD;
  bf16x8 qf0 = *(const bf16x8*)(Qp + (size_t)lrow * HD + quad * 8);
  bf16x8 qf1 = *(const bf16x8*)(Qp + (size_t)lrow * HD + 32 + quad * 8);

  AttnState st;
  #pragma unroll
  for (int i = 0; i < 4; ++i) st.o[i] = (f32x4){0.f, 0.f, 0.f, 0.f};
  st.l = 0.f;

  int kend = qt * 64;

  int kq = quad * 8;                          // loop-invariant per-lane sub-offset
  for (int kt = 0; kt <= kend; kt += 64) {
    const ushort* Kp = Kb + (size_t)kt * HD;          // uniform advance per step
    const ushort* Vp = Vb + (size_t)(kt >> 6) * 4096; // tile base (64*64 elems)

    bf16x8 kf0[4], kf1[4], vf0[4], vf1[4];
    #pragma unroll
    for (int c2 = 0; c2 < 4; ++c2) {
      const ushort* kr = Kp + (size_t)(c2 * 16 + lrow) * HD + kq;
      kf0[c2] = *(const bf16x8*)(kr);
      kf1[c2] = *(const bf16x8*)(kr + 32);
      const ushort* vr = Vp + (c2 * 16 + lrow) * 64 + kq;   // row=d, 128B stride
      vf0[c2] = *(const bf16x8*)(vr);
      vf1[c2] = *(const bf16x8*)(vr + 32);
    }

    if (kt < kend)
      attn_tile_compute<false>(q0, kt, qf0, qf1, kf0, kf1, vf0, vf1, st, lrow, quad);
    else
      attn_tile_compute<true>(q0, kt, qf0, qf1, kf0, kf1, vf0, vf1, st, lrow, quad);
  }

  {
    float l = st.l;
    l += __shfl_xor(l, 16);
    l += __shfl_xor(l, 32);
    float rl = 1.0f / l;
    #pragma unroll
    for (int e = 0; e < 4; ++e) {
      float rinv = __shfl(rl, quad * 4 + e);
      int q = q0 + quad * 4 + e;
      #pragma unroll
      for (int dt = 0; dt < 4; ++dt)
        ctx[((size_t)b * S_ + q) * DM + h * HD + dt * 16 + lrow] = f2bf(st.o[dt][e] * rinv);
    }
  }
}

// ---------------- launch ----------------
extern "C" void kernel_launch(void* const* d_in, const int* in_sizes, int n_in,
                              void* d_out, int out_size, void* d_ws, size_t ws_size,
                              hipStream_t stream) {
  const float* x  = (const float*)d_in[0];
  const float* Wq = (const float*)d_in[1];
  const float* Wk = (const float*)d_in[2];
  const float* Wv = (const float*)d_in[3];
  const float* Wo = (const float*)d_in[4];
  float* out = (float*)d_out;
  ushort* ws = (ushort*)d_ws;

  ushort* xb  = ws;                                   // 4M elem bf16 x
  ushort* wt  = xb + (size_t)M_ * DM;                 // 4 x 1M elem (Wq^T,Wk^T,Wv^T,Wo^T) bf16
  ushort* qkv = wt + (size_t)4 * DM * DM;             // Q,K [b,h,s,d]; V tile-major bf16
  ushort* ctx = qkv + (size_t)3 * M_ * DM;            // 4M elem [B,S,DM] bf16

  cvt_prep<<<dim3(16, 16, 5), dim3(64, 4), 0, stream>>>(x, Wq, Wk, Wv, Wo, wt, xb);
  gemm_qkv<<<dim3(DM / 128, M_ / 128, 3), 256, 0, stream>>>(xb, wt, qkv);
  attn_mfma<<<dim3(32 * B_ * NH), 256, 0, stream>>>(qkv, qkv + (size_t)M_ * DM,
                                                    qkv + (size_t)2 * M_ * DM, ctx);
  gemm_out<<<dim3(DM / 64, M_ / 128), 256, 0, stream>>>(ctx, wt + (size_t)3 * DM * DM, out);
}

// Round 14
// 170.154 us; speedup vs baseline: 1.5042x; 1.4910x over previous
//
#include <hip/hip_runtime.h>
#include <hip/hip_bf16.h>

#define DM 1024
#define NH 16
#define HD 64
#define B_ 2
#define S_ 2048
#define M_ (B_*S_)   // 4096

typedef __attribute__((ext_vector_type(8))) short bf16x8;
typedef __attribute__((ext_vector_type(4))) float f32x4;
typedef __attribute__((ext_vector_type(4))) unsigned uint32x4;
typedef __attribute__((ext_vector_type(2))) unsigned uint32x2;

__device__ __forceinline__ float bf2f(ushort u) {
  union { unsigned u32; float f; } c; c.u32 = ((unsigned)u) << 16; return c.f;
}
__device__ __forceinline__ ushort f2bf(float f) {
  union { float f; unsigned u32; } c; c.f = f;
  unsigned u = c.u32;
  unsigned r = (u + 0x7fffu + ((u >> 16) & 1u)) >> 16;
  return (ushort)r;
}
__device__ __forceinline__ unsigned fbits(float f) {
  union { float f; unsigned u; } c; c.f = f; return c.u;
}

// async global->LDS, 16 B per lane; LDS dest = wave-uniform base + lane*16
__device__ __forceinline__ void async16(const ushort* g, ushort* l) {
  __builtin_amdgcn_global_load_lds((const __attribute__((address_space(1))) void*)g,
                                   (__attribute__((address_space(3))) void*)l, 16, 0, 0);
}

// gfx950 cross-lane swaps via BUILTINS (not inline asm): permlane has a VALU-write ->
// permlane-read hazard requiring compiler-inserted wait states; the hazard recognizer
// can't see into inline asm (v9/v10 raw-asm miscompute; v11 builtins fixed it).
__device__ __forceinline__ void pswap32(unsigned& a, unsigned& b) {
  uint32x2 r = __builtin_amdgcn_permlane32_swap(a, b, false, false);
  a = r[0]; b = r[1];
}
__device__ __forceinline__ void pswap16(unsigned& a, unsigned& b) {
  uint32x2 r = __builtin_amdgcn_permlane16_swap(a, b, false, false);
  a = r[0]; b = r[1];
}

// ---- fused prep: z<4 -> fp32 W[k][n] -> bf16 Wt[n][k]; z==4 -> fp32 x -> bf16 ----
__global__ void cvt_prep(const float* __restrict__ x, const float* __restrict__ W0,
                         const float* __restrict__ W1, const float* __restrict__ W2,
                         const float* __restrict__ W3, ushort* __restrict__ wt,
                         ushort* __restrict__ xb) {
  __shared__ float tile[64][65];
  int z = blockIdx.z;
  int tx = threadIdx.x, ty = threadIdx.y;   // block (64,4)
  if (z == 4) {
    int tid = ty * 64 + tx;
    size_t base4 = ((size_t)blockIdx.y * 16 + blockIdx.x) * 4096;  // float4 units
    const float4* xv = (const float4*)x;
    ushort4* ov = (ushort4*)xb;
    #pragma unroll
    for (int k = 0; k < 16; ++k) {
      float4 v = xv[base4 + k * 256 + tid];
      ushort4 o;
      o.x = f2bf(v.x); o.y = f2bf(v.y); o.z = f2bf(v.z); o.w = f2bf(v.w);
      ov[base4 + k * 256 + tid] = o;
    }
    return;
  }
  const float* W = (z == 0) ? W0 : (z == 1) ? W1 : (z == 2) ? W2 : W3;
  ushort* Wt = wt + (size_t)z * (DM * DM);
  int c0 = blockIdx.x * 64, r0 = blockIdx.y * 64;
  #pragma unroll
  for (int i = ty; i < 64; i += 4) tile[i][tx] = W[(size_t)(r0 + i) * DM + c0 + tx];
  __syncthreads();
  #pragma unroll
  for (int i = ty; i < 64; i += 4) Wt[(size_t)(c0 + i) * DM + r0 + tx] = f2bf(tile[tx][i]);
}

// ---------------- MFMA GEMM: C[M][N] = A[M][K] * Bt[N][K]^T ----------------
// 128(M) x BN(N) tile, 4 waves (2x2), BK=32, global_load_lds width=16 staging.
// MODE 0: float C[m*DM+n]
// MODE 1: bf16 head layout C[((b*NH+h)*S_+s)*HD+d]             (Q, K)
// MODE 2: bf16 V^T layout C[((b*NH+h)*HD+d)*S_+s] via LDS transpose (coalesced)
template <int MODE, int BN>
__device__ __forceinline__ void gemm_body(const ushort* __restrict__ A,
                                          const ushort* __restrict__ Bt,
                                          ushort* __restrict__ Cb,
                                          float* __restrict__ Cf,
                                          ushort* As, ushort* Bs, ushort* Ts) {
  const int K = DM;
  constexpr int CN = BN / 32;                   // n-frags per wave
  int m0 = blockIdx.y * 128;
  int n0 = blockIdx.x * BN;
  int t = threadIdx.x;
  int lane = t & 63, wave = t >> 6;
  int wm = (wave >> 1) * 64, wn = (wave & 1) * (BN / 2);
  int lrow = lane & 15, quad = lane >> 4;

  int Ra = wave * 32;                           // A rows staged by this wave
  int Rb = wave * (BN / 4);                     // B rows staged by this wave
  int srow = lane >> 2, scol = (lane & 3) * 8;  // per-lane 16B chunk within 16-row group

  f32x4 acc[4][CN];
  #pragma unroll
  for (int r = 0; r < 4; ++r)
    #pragma unroll
    for (int c = 0; c < CN; ++c) acc[r][c] = (f32x4){0.f, 0.f, 0.f, 0.f};

  for (int k0 = 0; k0 < K; k0 += 32) {
    const ushort* ga = A + (size_t)(m0 + Ra + srow) * K + k0 + scol;
    const ushort* gb = Bt + (size_t)(n0 + Rb + srow) * K + k0 + scol;
    async16(ga,          As + Ra * 32);
    async16(ga + 16 * K, As + (Ra + 16) * 32);
    async16(gb,          Bs + Rb * 32);
    if (BN == 128) async16(gb + 16 * K, Bs + (Rb + 16) * 32);
    __syncthreads();

    bf16x8 af[4], bfr[CN];
    #pragma unroll
    for (int r = 0; r < 4; ++r)
      af[r] = *(const bf16x8*)(As + (wm + r * 16 + lrow) * 32 + quad * 8);
    #pragma unroll
    for (int c = 0; c < CN; ++c)
      bfr[c] = *(const bf16x8*)(Bs + (wn + c * 16 + lrow) * 32 + quad * 8);
    #pragma unroll
    for (int r = 0; r < 4; ++r)
      #pragma unroll
      for (int c = 0; c < CN; ++c)
        acc[r][c] = __builtin_amdgcn_mfma_f32_16x16x32_bf16(af[r], bfr[c], acc[r][c], 0, 0, 0);
    __syncthreads();
  }

  if constexpr (MODE == 2) {
    // transpose through LDS in two half-passes, then coalesced V^T rows.
    // Ts ALIASES As/Bs (dead after K-loop's trailing barrier).
    int bb = m0 >> 11;            // batch (block never straddles b)
    int s0base = m0 & 2047;
    #pragma unroll
    for (int H = 0; H < 2; ++H) {
      __syncthreads();            // Ts reuse guard (and As/Bs death guard on H=0)
      if ((wave >> 1) == H) {
        #pragma unroll
        for (int r = 0; r < 4; ++r)
          #pragma unroll
          for (int c = 0; c < 4; ++c) {
            uint2 pk;
            pk.x = (unsigned)f2bf(acc[r][c][0]) | ((unsigned)f2bf(acc[r][c][1]) << 16);
            pk.y = (unsigned)f2bf(acc[r][c][2]) | ((unsigned)f2bf(acc[r][c][3]) << 16);
            *(uint2*)(Ts + (wn + c * 16 + lrow) * 72 + r * 16 + quad * 4) = pk;
          }
      }
      __syncthreads();
      #pragma unroll
      for (int i = 0; i < 4; ++i) {
        int id = t + i * 256;
        int nn = id >> 3, col = (id & 7) * 8;
        uint4 v = *(const uint4*)(Ts + nn * 72 + col);
        int h2 = (n0 >> 6) + (nn >> 6), d2 = nn & 63;
        size_t dst = (((size_t)(bb * NH + h2)) * HD + d2) * (size_t)S_ + s0base + H * 64 + col;
        *(uint4*)(Cb + dst) = v;
      }
    }
  } else {
    // epilogue: C/D layout col=lane&15, row=quad*4+e
    #pragma unroll
    for (int r = 0; r < 4; ++r) {
      #pragma unroll
      for (int c = 0; c < CN; ++c) {
        #pragma unroll
        for (int e = 0; e < 4; ++e) {
          int m = m0 + wm + r * 16 + quad * 4 + e;
          int n = n0 + wn + c * 16 + lrow;
          if (MODE == 0) {
            Cf[(size_t)m * DM + n] = acc[r][c][e];
          } else {
            int b = m >> 11, s = m & 2047, h = n >> 6, d = n & 63;
            Cb[(((size_t)(b * NH + h)) * S_ + s) * HD + d] = f2bf(acc[r][c][e]);
          }
        }
      }
    }
  }
}

// single dispatch for Q, K, V (z = 0,1,2); Ts unioned with As/Bs -> 18.4 KB LDS
__global__ __launch_bounds__(256, 3) void gemm_qkv(const ushort* __restrict__ A,
                                                   const ushort* __restrict__ wt,
                                                   ushort* __restrict__ qkv) {
  __shared__ __align__(16) ushort smem[9216];   // As[0:4096) Bs[4096:8192); Ts aliases [0:9216)
  ushort* As = smem;
  ushort* Bs = smem + 4096;
  ushort* Ts = smem;
  int z = blockIdx.z;
  if (z < 2)
    gemm_body<1, 128>(A, wt + (size_t)z * (DM * DM), qkv + (size_t)z * ((size_t)M_ * DM),
                      nullptr, As, Bs, Ts);
  else
    gemm_body<2, 128>(A, wt + (size_t)2 * (DM * DM), qkv + (size_t)2 * ((size_t)M_ * DM),
                      nullptr, As, Bs, Ts);
}

// 128x64 tiles -> grid 512, 12 KB LDS, 3 blocks/CU target
__global__ __launch_bounds__(256, 3) void gemm_out(const ushort* __restrict__ A,
                                                   const ushort* __restrict__ wt,
                                                   float* __restrict__ C) {
  __shared__ __align__(16) ushort As[128 * 32];
  __shared__ __align__(16) ushort Bs[64 * 32];
  gemm_body<0, 64>(A, wt, nullptr, C, As, Bs, nullptr);
}

// ---------------- MFMA flash attention v17: v11 revert + setprio A/B ----------------
// v15/v16 post-mortem: zero-LDS refuted — fragment-shaped direct loads fragment into
// ~16 cache-line txns per instruction for BOTH K and V (v16's coalesced tile-major V
// changed nothing: 124.5 vs 126.4us). The per-block LDS staging (1 coalesced copy
// shared by 4 waves) was real work. Per the round-10 decision rule: revert to the
// best proven attn (v11, <42.5us, total 175.2) and pivot to the GEMM path next.
// One isolated addition: s_setprio(1) around the MFMA clusters (T5). m190/m191:
// null on barrier-lockstep single-block GEMM, +4-7% on attn with independent wave
// progress. v11 runs 4 INDEPENDENT blocks/CU -> the SIMD hosts waves of different
// blocks at different phases -> setprio has something to arbitrate. Pure hint; A/B
// readable against v11's <42.5 baseline.
#define EXPC 0.18033688011f   // 0.125 * log2(e)

struct AttnState {
  f32x4 o[4];
  float l;
};

template <bool MASKED>
__device__ __forceinline__ void attn_tile_compute(
    int q0, int kt, bf16x8 qf0, bf16x8 qf1,
    const bf16x8 kf0[4], const bf16x8 kf1[4],
    const bf16x8 vf0[4], const bf16x8 vf1[4],
    AttnState& st, int lrow, int quad) {
  f32x4 s[4];
  __builtin_amdgcn_s_setprio(1);
  #pragma unroll
  for (int c = 0; c < 4; ++c) {
    f32x4 z = (f32x4){0.f, 0.f, 0.f, 0.f};
    z = __builtin_amdgcn_mfma_f32_16x16x32_bf16(kf0[c], qf0, z, 0, 0, 0);
    z = __builtin_amdgcn_mfma_f32_16x16x32_bf16(kf1[c], qf1, z, 0, 0, 0);
    s[c] = z;
  }
  __builtin_amdgcn_s_setprio(0);
  int q = q0 + lrow;
  unsigned w0[4], w1[4];   // W[c][0], W[c][1]: packed bf16 pairs, keys 16c+4*quad+{0,1},{2,3}
  #pragma unroll
  for (int c = 0; c < 4; ++c) {
    float pv[4];
    #pragma unroll
    for (int e = 0; e < 4; ++e) {
      float v = __builtin_amdgcn_exp2f(s[c][e] * EXPC);
      if (MASKED) {
        int key = kt + c * 16 + quad * 4 + e;
        v = (key <= q) ? v : 0.f;
      }
      pv[e] = v;
      st.l += v;
    }
    w0[c] = __builtin_amdgcn_perm(fbits(pv[1]), fbits(pv[0]), 0x07060302u);
    w1[c] = __builtin_amdgcn_perm(fbits(pv[3]), fbits(pv[2]), 0x07060302u);
  }

  // redistribute: pair (W[c], W[c+1]) -> permlane32_swap + permlane16_swap.
  unsigned a0 = w0[0], b0 = w0[1]; pswap32(a0, b0); pswap16(a0, b0);
  unsigned a1 = w1[0], b1 = w1[1]; pswap32(a1, b1); pswap16(a1, b1);
  unsigned c0 = w0[2], d0 = w0[3]; pswap32(c0, d0); pswap16(c0, d0);
  unsigned c1 = w1[2], d1 = w1[3]; pswap32(c1, d1); pswap16(c1, d1);
  union { uint32x4 u; bf16x8 b; } P0, P1;
  P0.u = (uint32x4){a0, a1, b0, b1};   // keys 8*quad+0..7   (A-frag, k=0..31)
  P1.u = (uint32x4){c0, c1, d0, d1};   // keys 32+8*quad+0..7 (A-frag, k=32..63)

  __builtin_amdgcn_s_setprio(1);
  #pragma unroll
  for (int dt = 0; dt < 4; ++dt) {
    st.o[dt] = __builtin_amdgcn_mfma_f32_16x16x32_bf16(P0.b, vf0[dt], st.o[dt], 0, 0, 0);
    st.o[dt] = __builtin_amdgcn_mfma_f32_16x16x32_bf16(P1.b, vf1[dt], st.o[dt], 0, 0, 0);
  }
  __builtin_amdgcn_s_setprio(0);
}

__global__ __launch_bounds__(256, 2) void attn_mfma(const ushort* __restrict__ Q,
                                                    const ushort* __restrict__ Kmat,
                                                    const ushort* __restrict__ Vt,
                                                    ushort* __restrict__ ctx) {
  __shared__ __align__(16) ushort Ks[2][64 * 72];    // [key][d]
  __shared__ __align__(16) ushort Vs[2][64 * 72];    // [d][key]
  int t = threadIdx.x;
  int lane = t & 63, wave = t >> 6;
  int lrow = lane & 15, quad = lane >> 4;
  int n = blockIdx.x;                  // 0..1023
  int qt = 31 - (n >> 5);              // heavy tiles dispatch first
  int bh = n & 31;                     // same head -> same XCD (n%8 == bh%8)
  const ushort* Kb = Kmat + (size_t)bh * S_ * HD;
  const ushort* Vb = Vt + (size_t)bh * HD * S_;
  int b = bh >> 4, h = bh & 15;

  int r0 = t >> 3, s0 = (t & 7) * 8;              // chunk t
  int r1 = (t + 256) >> 3, s1 = s0;               // chunk t+256

  int q0 = qt * 64 + wave * 16;
  const ushort* Qp = Q + ((size_t)bh * S_ + q0) * HD;
  bf16x8 qf0 = *(const bf16x8*)(Qp + (size_t)lrow * HD + quad * 8);
  bf16x8 qf1 = *(const bf16x8*)(Qp + (size_t)lrow * HD + 32 + quad * 8);

  AttnState st;
  #pragma unroll
  for (int i = 0; i < 4; ++i) st.o[i] = (f32x4){0.f, 0.f, 0.f, 0.f};
  st.l = 0.f;

  int kend = qt * 64;

  {
    uint4 ka = *(const uint4*)(Kb + (size_t)r0 * HD + s0);
    uint4 kb2 = *(const uint4*)(Kb + (size_t)r1 * HD + s1);
    uint4 va = *(const uint4*)(Vb + (size_t)r0 * S_ + s0);
    uint4 vb2 = *(const uint4*)(Vb + (size_t)r1 * S_ + s1);
    *(uint4*)(Ks[0] + r0 * 72 + s0) = ka;
    *(uint4*)(Ks[0] + r1 * 72 + s1) = kb2;
    *(uint4*)(Vs[0] + r0 * 72 + s0) = va;
    *(uint4*)(Vs[0] + r1 * 72 + s1) = vb2;
  }
  __syncthreads();

  for (int kt = 0; kt <= kend; kt += 64) {
    int cur = (kt >> 6) & 1, nxt = cur ^ 1;
    bool has_next = (kt < kend);

    uint4 ka, kb2, va, vb2;
    if (has_next) {
      int ktn = kt + 64;
      ka  = *(const uint4*)(Kb + (size_t)(ktn + r0) * HD + s0);
      kb2 = *(const uint4*)(Kb + (size_t)(ktn + r1) * HD + s1);
      va  = *(const uint4*)(Vb + (size_t)r0 * S_ + ktn + s0);
      vb2 = *(const uint4*)(Vb + (size_t)r1 * S_ + ktn + s1);
    }

    bf16x8 kf0[4], kf1[4], vf0[4], vf1[4];
    #pragma unroll
    for (int c2 = 0; c2 < 4; ++c2) {
      const ushort* kr = Ks[cur] + (c2 * 16 + lrow) * 72;
      kf0[c2] = *(const bf16x8*)(kr + quad * 8);
      kf1[c2] = *(const bf16x8*)(kr + 32 + quad * 8);
      const ushort* vr = Vs[cur] + (c2 * 16 + lrow) * 72;
      vf0[c2] = *(const bf16x8*)(vr + quad * 8);
      vf1[c2] = *(const bf16x8*)(vr + 32 + quad * 8);
    }

    if (kt < kend)
      attn_tile_compute<false>(q0, kt, qf0, qf1, kf0, kf1, vf0, vf1, st, lrow, quad);
    else
      attn_tile_compute<true>(q0, kt, qf0, qf1, kf0, kf1, vf0, vf1, st, lrow, quad);

    __syncthreads();   // all waves done reading Ks/Vs[cur] before any rewrite

    if (has_next) {
      *(uint4*)(Ks[nxt] + r0 * 72 + s0) = ka;
      *(uint4*)(Ks[nxt] + r1 * 72 + s1) = kb2;
      *(uint4*)(Vs[nxt] + r0 * 72 + s0) = va;
      *(uint4*)(Vs[nxt] + r1 * 72 + s1) = vb2;
    }
    __syncthreads();
  }

  {
    float l = st.l;
    l += __shfl_xor(l, 16);
    l += __shfl_xor(l, 32);
    float rl = 1.0f / l;
    #pragma unroll
    for (int e = 0; e < 4; ++e) {
      float rinv = __shfl(rl, quad * 4 + e);
      int q = q0 + quad * 4 + e;
      #pragma unroll
      for (int dt = 0; dt < 4; ++dt)
        ctx[((size_t)b * S_ + q) * DM + h * HD + dt * 16 + lrow] = f2bf(st.o[dt][e] * rinv);
    }
  }
}

// ---------------- launch ----------------
extern "C" void kernel_launch(void* const* d_in, const int* in_sizes, int n_in,
                              void* d_out, int out_size, void* d_ws, size_t ws_size,
                              hipStream_t stream) {
  const float* x  = (const float*)d_in[0];
  const float* Wq = (const float*)d_in[1];
  const float* Wk = (const float*)d_in[2];
  const float* Wv = (const float*)d_in[3];
  const float* Wo = (const float*)d_in[4];
  float* out = (float*)d_out;
  ushort* ws = (ushort*)d_ws;

  ushort* xb  = ws;                                   // 4M elem bf16 x
  ushort* wt  = xb + (size_t)M_ * DM;                 // 4 x 1M elem (Wq^T,Wk^T,Wv^T,Wo^T) bf16
  ushort* qkv = wt + (size_t)4 * DM * DM;             // Q,K [b,h,s,d]; V^T [b,h,d,s] bf16
  ushort* ctx = qkv + (size_t)3 * M_ * DM;            // 4M elem [B,S,DM] bf16

  cvt_prep<<<dim3(16, 16, 5), dim3(64, 4), 0, stream>>>(x, Wq, Wk, Wv, Wo, wt, xb);
  gemm_qkv<<<dim3(DM / 128, M_ / 128, 3), 256, 0, stream>>>(xb, wt, qkv);
  attn_mfma<<<dim3(32 * B_ * NH), 256, 0, stream>>>(qkv, qkv + (size_t)M_ * DM,
                                                    qkv + (size_t)2 * M_ * DM, ctx);
  gemm_out<<<dim3(DM / 64, M_ / 128), 256, 0, stream>>>(ctx, wt + (size_t)3 * DM * DM, out);
}

// Round 15
// 168.524 us; speedup vs baseline: 1.5187x; 1.0097x over previous
//
#include <hip/hip_runtime.h>
#include <hip/hip_bf16.h>

#define DM 1024
#define NH 16
#define HD 64
#define B_ 2
#define S_ 2048
#define M_ (B_*S_)   // 4096

typedef __attribute__((ext_vector_type(8))) short bf16x8;
typedef __attribute__((ext_vector_type(4))) float f32x4;
typedef __attribute__((ext_vector_type(4))) unsigned uint32x4;
typedef __attribute__((ext_vector_type(2))) unsigned uint32x2;

__device__ __forceinline__ float bf2f(ushort u) {
  union { unsigned u32; float f; } c; c.u32 = ((unsigned)u) << 16; return c.f;
}
__device__ __forceinline__ ushort f2bf(float f) {
  union { float f; unsigned u32; } c; c.f = f;
  unsigned u = c.u32;
  unsigned r = (u + 0x7fffu + ((u >> 16) & 1u)) >> 16;
  return (ushort)r;
}
__device__ __forceinline__ unsigned fbits(float f) {
  union { float f; unsigned u; } c; c.f = f; return c.u;
}

// async global->LDS, 16 B per lane; LDS dest = wave-uniform base + lane*16
__device__ __forceinline__ void async16(const ushort* g, ushort* l) {
  __builtin_amdgcn_global_load_lds((const __attribute__((address_space(1))) void*)g,
                                   (__attribute__((address_space(3))) void*)l, 16, 0, 0);
}

// gfx950 cross-lane swaps via BUILTINS (not inline asm): permlane has a VALU-write ->
// permlane-read hazard requiring compiler-inserted wait states; the hazard recognizer
// can't see into inline asm (v9/v10 raw-asm miscompute; v11 builtins fixed it).
__device__ __forceinline__ void pswap32(unsigned& a, unsigned& b) {
  uint32x2 r = __builtin_amdgcn_permlane32_swap(a, b, false, false);
  a = r[0]; b = r[1];
}
__device__ __forceinline__ void pswap16(unsigned& a, unsigned& b) {
  uint32x2 r = __builtin_amdgcn_permlane16_swap(a, b, false, false);
  a = r[0]; b = r[1];
}

// ---- fused prep: z<4 -> fp32 W[k][n] -> bf16 Wt[n][k]; z==4 -> fp32 x -> bf16 ----
__global__ void cvt_prep(const float* __restrict__ x, const float* __restrict__ W0,
                         const float* __restrict__ W1, const float* __restrict__ W2,
                         const float* __restrict__ W3, ushort* __restrict__ wt,
                         ushort* __restrict__ xb) {
  __shared__ float tile[64][65];
  int z = blockIdx.z;
  int tx = threadIdx.x, ty = threadIdx.y;   // block (64,4)
  if (z == 4) {
    int tid = ty * 64 + tx;
    size_t base4 = ((size_t)blockIdx.y * 16 + blockIdx.x) * 4096;  // float4 units
    const float4* xv = (const float4*)x;
    ushort4* ov = (ushort4*)xb;
    #pragma unroll
    for (int k = 0; k < 16; ++k) {
      float4 v = xv[base4 + k * 256 + tid];
      ushort4 o;
      o.x = f2bf(v.x); o.y = f2bf(v.y); o.z = f2bf(v.z); o.w = f2bf(v.w);
      ov[base4 + k * 256 + tid] = o;
    }
    return;
  }
  const float* W = (z == 0) ? W0 : (z == 1) ? W1 : (z == 2) ? W2 : W3;
  ushort* Wt = wt + (size_t)z * (DM * DM);
  int c0 = blockIdx.x * 64, r0 = blockIdx.y * 64;
  #pragma unroll
  for (int i = ty; i < 64; i += 4) tile[i][tx] = W[(size_t)(r0 + i) * DM + c0 + tx];
  __syncthreads();
  #pragma unroll
  for (int i = ty; i < 64; i += 4) Wt[(size_t)(c0 + i) * DM + r0 + tx] = f2bf(tile[tx][i]);
}

// ---------------- MFMA GEMM: C[M][N] = A[M][K] * Bt[N][K]^T ----------------
// 128(M) x BN(N) tile, 4 waves (2x2), BK=32, global_load_lds width=16 staging.
// MODE 0: float C[m*DM+n]
// MODE 1: bf16 head layout C[((b*NH+h)*S_+s)*HD+d]             (Q, K)
// MODE 2: bf16 V^T layout C[((b*NH+h)*HD+d)*S_+s] via LDS transpose (coalesced)
template <int MODE, int BN>
__device__ __forceinline__ void gemm_body(const ushort* __restrict__ A,
                                          const ushort* __restrict__ Bt,
                                          ushort* __restrict__ Cb,
                                          float* __restrict__ Cf,
                                          ushort* As, ushort* Bs, ushort* Ts) {
  const int K = DM;
  constexpr int CN = BN / 32;                   // n-frags per wave
  int m0 = blockIdx.y * 128;
  int n0 = blockIdx.x * BN;
  int t = threadIdx.x;
  int lane = t & 63, wave = t >> 6;
  int wm = (wave >> 1) * 64, wn = (wave & 1) * (BN / 2);
  int lrow = lane & 15, quad = lane >> 4;

  int Ra = wave * 32;                           // A rows staged by this wave
  int Rb = wave * (BN / 4);                     // B rows staged by this wave
  int srow = lane >> 2, scol = (lane & 3) * 8;  // per-lane 16B chunk within 16-row group

  f32x4 acc[4][CN];
  #pragma unroll
  for (int r = 0; r < 4; ++r)
    #pragma unroll
    for (int c = 0; c < CN; ++c) acc[r][c] = (f32x4){0.f, 0.f, 0.f, 0.f};

  for (int k0 = 0; k0 < K; k0 += 32) {
    const ushort* ga = A + (size_t)(m0 + Ra + srow) * K + k0 + scol;
    const ushort* gb = Bt + (size_t)(n0 + Rb + srow) * K + k0 + scol;
    async16(ga,          As + Ra * 32);
    async16(ga + 16 * K, As + (Ra + 16) * 32);
    async16(gb,          Bs + Rb * 32);
    if (BN == 128) async16(gb + 16 * K, Bs + (Rb + 16) * 32);
    __syncthreads();

    bf16x8 af[4], bfr[CN];
    #pragma unroll
    for (int r = 0; r < 4; ++r)
      af[r] = *(const bf16x8*)(As + (wm + r * 16 + lrow) * 32 + quad * 8);
    #pragma unroll
    for (int c = 0; c < CN; ++c)
      bfr[c] = *(const bf16x8*)(Bs + (wn + c * 16 + lrow) * 32 + quad * 8);
    #pragma unroll
    for (int r = 0; r < 4; ++r)
      #pragma unroll
      for (int c = 0; c < CN; ++c)
        acc[r][c] = __builtin_amdgcn_mfma_f32_16x16x32_bf16(af[r], bfr[c], acc[r][c], 0, 0, 0);
    __syncthreads();
  }

  if constexpr (MODE == 2) {
    // transpose through LDS in two half-passes, then coalesced V^T rows.
    // Ts ALIASES As/Bs (dead after K-loop's trailing barrier).
    int bb = m0 >> 11;            // batch (block never straddles b)
    int s0base = m0 & 2047;
    #pragma unroll
    for (int H = 0; H < 2; ++H) {
      __syncthreads();            // Ts reuse guard (and As/Bs death guard on H=0)
      if ((wave >> 1) == H) {
        #pragma unroll
        for (int r = 0; r < 4; ++r)
          #pragma unroll
          for (int c = 0; c < 4; ++c) {
            uint2 pk;
            pk.x = (unsigned)f2bf(acc[r][c][0]) | ((unsigned)f2bf(acc[r][c][1]) << 16);
            pk.y = (unsigned)f2bf(acc[r][c][2]) | ((unsigned)f2bf(acc[r][c][3]) << 16);
            *(uint2*)(Ts + (wn + c * 16 + lrow) * 72 + r * 16 + quad * 4) = pk;
          }
      }
      __syncthreads();
      #pragma unroll
      for (int i = 0; i < 4; ++i) {
        int id = t + i * 256;
        int nn = id >> 3, col = (id & 7) * 8;
        uint4 v = *(const uint4*)(Ts + nn * 72 + col);
        int h2 = (n0 >> 6) + (nn >> 6), d2 = nn & 63;
        size_t dst = (((size_t)(bb * NH + h2)) * HD + d2) * (size_t)S_ + s0base + H * 64 + col;
        *(uint4*)(Cb + dst) = v;
      }
    }
  } else {
    // epilogue: C/D layout col=lane&15, row=quad*4+e
    #pragma unroll
    for (int r = 0; r < 4; ++r) {
      #pragma unroll
      for (int c = 0; c < CN; ++c) {
        #pragma unroll
        for (int e = 0; e < 4; ++e) {
          int m = m0 + wm + r * 16 + quad * 4 + e;
          int n = n0 + wn + c * 16 + lrow;
          if (MODE == 0) {
            Cf[(size_t)m * DM + n] = acc[r][c][e];
          } else {
            int b = m >> 11, s = m & 2047, h = n >> 6, d = n & 63;
            Cb[(((size_t)(b * NH + h)) * S_ + s) * HD + d] = f2bf(acc[r][c][e]);
          }
        }
      }
    }
  }
}

// single dispatch for Q, K, V (z = 0,1,2); Ts unioned with As/Bs -> 18.4 KB LDS
__global__ __launch_bounds__(256, 3) void gemm_qkv(const ushort* __restrict__ A,
                                                   const ushort* __restrict__ wt,
                                                   ushort* __restrict__ qkv) {
  __shared__ __align__(16) ushort smem[9216];   // As[0:4096) Bs[4096:8192); Ts aliases [0:9216)
  ushort* As = smem;
  ushort* Bs = smem + 4096;
  ushort* Ts = smem;
  int z = blockIdx.z;
  if (z < 2)
    gemm_body<1, 128>(A, wt + (size_t)z * (DM * DM), qkv + (size_t)z * ((size_t)M_ * DM),
                      nullptr, As, Bs, Ts);
  else
    gemm_body<2, 128>(A, wt + (size_t)2 * (DM * DM), qkv + (size_t)2 * ((size_t)M_ * DM),
                      nullptr, As, Bs, Ts);
}

// 128x64 tiles -> grid 512, 12 KB LDS, 3 blocks/CU target
__global__ __launch_bounds__(256, 3) void gemm_out(const ushort* __restrict__ A,
                                                   const ushort* __restrict__ wt,
                                                   float* __restrict__ C) {
  __shared__ __align__(16) ushort As[128 * 32];
  __shared__ __align__(16) ushort Bs[64 * 32];
  gemm_body<0, 64>(A, wt, nullptr, C, As, Bs, nullptr);
}

// ---------------- MFMA flash attention v18: single-barrier double-buffer ----------------
// v17 post-mortem: setprio CONFIRMED (+~7us: total 175.2->170.2 with rest-of-pipeline
// constant at ~133; attn ~43.8 -> ~37). All kernels now < the 43us fill cutoff.
// v18: remove the v10 "hardening" mid-loop barrier. It was added chasing the v9 bug,
// which was root-caused to the inline-asm permlane hazard (fixed via builtins in v11) —
// NOT a buffer race. Single-barrier correctness argument: within iter i, writes target
// nxt while reads target cur (disjoint); the end-of-iter barrier orders iter-i writes
// before iter-i+1 reads of that buffer, and iter-i+1's writes to old-cur start only
// after the barrier all iter-i reads precede. v7/v8 ran exactly this structure.
// Halves barrier convoys: 2 -> 1 per K-step (~150-300 cyc each, 4-wave convoy).
#define EXPC 0.18033688011f   // 0.125 * log2(e)

struct AttnState {
  f32x4 o[4];
  float l;
};

template <bool MASKED>
__device__ __forceinline__ void attn_tile_compute(
    int q0, int kt, bf16x8 qf0, bf16x8 qf1,
    const bf16x8 kf0[4], const bf16x8 kf1[4],
    const bf16x8 vf0[4], const bf16x8 vf1[4],
    AttnState& st, int lrow, int quad) {
  f32x4 s[4];
  __builtin_amdgcn_s_setprio(1);
  #pragma unroll
  for (int c = 0; c < 4; ++c) {
    f32x4 z = (f32x4){0.f, 0.f, 0.f, 0.f};
    z = __builtin_amdgcn_mfma_f32_16x16x32_bf16(kf0[c], qf0, z, 0, 0, 0);
    z = __builtin_amdgcn_mfma_f32_16x16x32_bf16(kf1[c], qf1, z, 0, 0, 0);
    s[c] = z;
  }
  __builtin_amdgcn_s_setprio(0);
  int q = q0 + lrow;
  unsigned w0[4], w1[4];   // W[c][0], W[c][1]: packed bf16 pairs, keys 16c+4*quad+{0,1},{2,3}
  #pragma unroll
  for (int c = 0; c < 4; ++c) {
    float pv[4];
    #pragma unroll
    for (int e = 0; e < 4; ++e) {
      float v = __builtin_amdgcn_exp2f(s[c][e] * EXPC);
      if (MASKED) {
        int key = kt + c * 16 + quad * 4 + e;
        v = (key <= q) ? v : 0.f;
      }
      pv[e] = v;
      st.l += v;
    }
    w0[c] = __builtin_amdgcn_perm(fbits(pv[1]), fbits(pv[0]), 0x07060302u);
    w1[c] = __builtin_amdgcn_perm(fbits(pv[3]), fbits(pv[2]), 0x07060302u);
  }

  // redistribute: pair (W[c], W[c+1]) -> permlane32_swap + permlane16_swap.
  unsigned a0 = w0[0], b0 = w0[1]; pswap32(a0, b0); pswap16(a0, b0);
  unsigned a1 = w1[0], b1 = w1[1]; pswap32(a1, b1); pswap16(a1, b1);
  unsigned c0 = w0[2], d0 = w0[3]; pswap32(c0, d0); pswap16(c0, d0);
  unsigned c1 = w1[2], d1 = w1[3]; pswap32(c1, d1); pswap16(c1, d1);
  union { uint32x4 u; bf16x8 b; } P0, P1;
  P0.u = (uint32x4){a0, a1, b0, b1};   // keys 8*quad+0..7   (A-frag, k=0..31)
  P1.u = (uint32x4){c0, c1, d0, d1};   // keys 32+8*quad+0..7 (A-frag, k=32..63)

  __builtin_amdgcn_s_setprio(1);
  #pragma unroll
  for (int dt = 0; dt < 4; ++dt) {
    st.o[dt] = __builtin_amdgcn_mfma_f32_16x16x32_bf16(P0.b, vf0[dt], st.o[dt], 0, 0, 0);
    st.o[dt] = __builtin_amdgcn_mfma_f32_16x16x32_bf16(P1.b, vf1[dt], st.o[dt], 0, 0, 0);
  }
  __builtin_amdgcn_s_setprio(0);
}

__global__ __launch_bounds__(256, 2) void attn_mfma(const ushort* __restrict__ Q,
                                                    const ushort* __restrict__ Kmat,
                                                    const ushort* __restrict__ Vt,
                                                    ushort* __restrict__ ctx) {
  __shared__ __align__(16) ushort Ks[2][64 * 72];    // [key][d]
  __shared__ __align__(16) ushort Vs[2][64 * 72];    // [d][key]
  int t = threadIdx.x;
  int lane = t & 63, wave = t >> 6;
  int lrow = lane & 15, quad = lane >> 4;
  int n = blockIdx.x;                  // 0..1023
  int qt = 31 - (n >> 5);              // heavy tiles dispatch first
  int bh = n & 31;                     // same head -> same XCD (n%8 == bh%8)
  const ushort* Kb = Kmat + (size_t)bh * S_ * HD;
  const ushort* Vb = Vt + (size_t)bh * HD * S_;
  int b = bh >> 4, h = bh & 15;

  int r0 = t >> 3, s0 = (t & 7) * 8;              // chunk t
  int r1 = (t + 256) >> 3, s1 = s0;               // chunk t+256

  int q0 = qt * 64 + wave * 16;
  const ushort* Qp = Q + ((size_t)bh * S_ + q0) * HD;
  bf16x8 qf0 = *(const bf16x8*)(Qp + (size_t)lrow * HD + quad * 8);
  bf16x8 qf1 = *(const bf16x8*)(Qp + (size_t)lrow * HD + 32 + quad * 8);

  AttnState st;
  #pragma unroll
  for (int i = 0; i < 4; ++i) st.o[i] = (f32x4){0.f, 0.f, 0.f, 0.f};
  st.l = 0.f;

  int kend = qt * 64;

  {
    uint4 ka = *(const uint4*)(Kb + (size_t)r0 * HD + s0);
    uint4 kb2 = *(const uint4*)(Kb + (size_t)r1 * HD + s1);
    uint4 va = *(const uint4*)(Vb + (size_t)r0 * S_ + s0);
    uint4 vb2 = *(const uint4*)(Vb + (size_t)r1 * S_ + s1);
    *(uint4*)(Ks[0] + r0 * 72 + s0) = ka;
    *(uint4*)(Ks[0] + r1 * 72 + s1) = kb2;
    *(uint4*)(Vs[0] + r0 * 72 + s0) = va;
    *(uint4*)(Vs[0] + r1 * 72 + s1) = vb2;
  }
  __syncthreads();

  for (int kt = 0; kt <= kend; kt += 64) {
    int cur = (kt >> 6) & 1, nxt = cur ^ 1;
    bool has_next = (kt < kend);

    uint4 ka, kb2, va, vb2;
    if (has_next) {
      int ktn = kt + 64;
      ka  = *(const uint4*)(Kb + (size_t)(ktn + r0) * HD + s0);
      kb2 = *(const uint4*)(Kb + (size_t)(ktn + r1) * HD + s1);
      va  = *(const uint4*)(Vb + (size_t)r0 * S_ + ktn + s0);
      vb2 = *(const uint4*)(Vb + (size_t)r1 * S_ + ktn + s1);
    }

    bf16x8 kf0[4], kf1[4], vf0[4], vf1[4];
    #pragma unroll
    for (int c2 = 0; c2 < 4; ++c2) {
      const ushort* kr = Ks[cur] + (c2 * 16 + lrow) * 72;
      kf0[c2] = *(const bf16x8*)(kr + quad * 8);
      kf1[c2] = *(const bf16x8*)(kr + 32 + quad * 8);
      const ushort* vr = Vs[cur] + (c2 * 16 + lrow) * 72;
      vf0[c2] = *(const bf16x8*)(vr + quad * 8);
      vf1[c2] = *(const bf16x8*)(vr + 32 + quad * 8);
    }

    if (kt < kend)
      attn_tile_compute<false>(q0, kt, qf0, qf1, kf0, kf1, vf0, vf1, st, lrow, quad);
    else
      attn_tile_compute<true>(q0, kt, qf0, qf1, kf0, kf1, vf0, vf1, st, lrow, quad);

    if (has_next) {
      *(uint4*)(Ks[nxt] + r0 * 72 + s0) = ka;
      *(uint4*)(Ks[nxt] + r1 * 72 + s1) = kb2;
      *(uint4*)(Vs[nxt] + r0 * 72 + s0) = va;
      *(uint4*)(Vs[nxt] + r1 * 72 + s1) = vb2;
    }
    __syncthreads();
  }

  {
    float l = st.l;
    l += __shfl_xor(l, 16);
    l += __shfl_xor(l, 32);
    float rl = 1.0f / l;
    #pragma unroll
    for (int e = 0; e < 4; ++e) {
      float rinv = __shfl(rl, quad * 4 + e);
      int q = q0 + quad * 4 + e;
      #pragma unroll
      for (int dt = 0; dt < 4; ++dt)
        ctx[((size_t)b * S_ + q) * DM + h * HD + dt * 16 + lrow] = f2bf(st.o[dt][e] * rinv);
    }
  }
}

// ---------------- launch ----------------
extern "C" void kernel_launch(void* const* d_in, const int* in_sizes, int n_in,
                              void* d_out, int out_size, void* d_ws, size_t ws_size,
                              hipStream_t stream) {
  const float* x  = (const float*)d_in[0];
  const float* Wq = (const float*)d_in[1];
  const float* Wk = (const float*)d_in[2];
  const float* Wv = (const float*)d_in[3];
  const float* Wo = (const float*)d_in[4];
  float* out = (float*)d_out;
  ushort* ws = (ushort*)d_ws;

  ushort* xb  = ws;                                   // 4M elem bf16 x
  ushort* wt  = xb + (size_t)M_ * DM;                 // 4 x 1M elem (Wq^T,Wk^T,Wv^T,Wo^T) bf16
  ushort* qkv = wt + (size_t)4 * DM * DM;             // Q,K [b,h,s,d]; V^T [b,h,d,s] bf16
  ushort* ctx = qkv + (size_t)3 * M_ * DM;            // 4M elem [B,S,DM] bf16

  cvt_prep<<<dim3(16, 16, 5), dim3(64, 4), 0, stream>>>(x, Wq, Wk, Wv, Wo, wt, xb);
  gemm_qkv<<<dim3(DM / 128, M_ / 128, 3), 256, 0, stream>>>(xb, wt, qkv);
  attn_mfma<<<dim3(32 * B_ * NH), 256, 0, stream>>>(qkv, qkv + (size_t)M_ * DM,
                                                    qkv + (size_t)2 * M_ * DM, ctx);
  gemm_out<<<dim3(DM / 64, M_ / 128), 256, 0, stream>>>(ctx, wt + (size_t)3 * DM * DM, out);
}